// Round 4
// baseline (318.000 us; speedup 1.0000x reference)
//
#include <hip/hip_runtime.h>
#include <hip/hip_bf16.h>
#include <stdint.h>

// Problem constants (from reference)
#define B_ 8
#define T_ 1500
#define TPAD 1504         // T_ padded to multiple of 16 for the scan batcher
#define H_ 1280
#define HM1 1279
#define OUT_ 4096
#define MTOK 375
#define MROWS (B_*MTOK)   // 3000
#define KPAD 1280         // shared K for both GEMMs (cif K=1279 zero-padded)

typedef __attribute__((ext_vector_type(8))) short bf16x8;  // 8 bf16 = 4 VGPRs
typedef __attribute__((ext_vector_type(4))) float f32x4;
typedef unsigned short u16;
typedef unsigned int u32;

static __device__ __forceinline__ u16 f2bf(float f) {
    unsigned int x = __float_as_uint(f);
    unsigned int r = (x + 0x7fffu + ((x >> 16) & 1u)) >> 16;
    return (u16)r;
}
static __device__ __forceinline__ void glds16(const u16* g, u16* l) {
    __builtin_amdgcn_global_load_lds(
        (const __attribute__((address_space(1))) void*)g,
        (__attribute__((address_space(3))) void*)l, 16, 0, 0);
}

// Front kernel: blocks 0..7 = fused sigmoid+scan+post-pass (one per batch);
// blocks 8.. = both weight transposes (text transpose folds in rms_w).
__global__ __launch_bounds__(256) void k_front(
    const float* __restrict__ audio, const int* __restrict__ num_tokens,
    const float* __restrict__ rms_w,
    float* __restrict__ pred_out,
    int* __restrict__ tok0, float* __restrict__ w0a,
    int* __restrict__ tok1, float* __restrict__ w1a,
    int* __restrict__ lo, int* __restrict__ hi,
    float* __restrict__ h_sumsq,
    const float* __restrict__ cif_w, const float* __restrict__ text_w,
    u16* __restrict__ cwt, u16* __restrict__ twt)
{
    __shared__ float smem[3524];   // union: scan(3521 floats) / transpose tile(32x33)
    const int tid = threadIdx.x;

    if (blockIdx.x < B_) {
        // ================= CIF scan branch =================
        const int b = blockIdx.x;
        float* al = smem;                    // [1504] (1500 + 4 zero pad)
        float* ip = smem + TPAD;             // [1504]
        float* red = smem + 2*TPAD;          // [256]
        int*   redI = (int*)(smem + 2*TPAD + 256);   // [256]
        float* scale_sh = smem + 2*TPAD + 512;

        // phase 1: sigmoid + pred + scale
        float sig[6];
        float s = 0.f;
        #pragma unroll
        for (int i = 0; i < 6; ++i) {
            int t = tid + i*256;
            sig[i] = 0.f;
            if (t < T_) {
                float x = audio[((size_t)b*T_ + t)*H_ + (H_-1)];
                sig[i] = 1.f / (1.f + expf(-x));
                s += sig[i];
            }
        }
        red[tid] = s; __syncthreads();
        for (int off = 128; off > 0; off >>= 1) {
            if (tid < off) red[tid] += red[tid+off];
            __syncthreads();
        }
        if (tid == 0) {
            float pred = red[0];
            pred_out[b] = pred;
            *scale_sh = (float)num_tokens[b] / pred;
        }
        __syncthreads();
        float scale = *scale_sh;
        #pragma unroll
        for (int i = 0; i < 6; ++i) {
            int t = tid + i*256;
            if (t < T_) al[t] = sig[i] * scale;
        }
        if (tid < TPAD - T_) al[T_ + tid] = 0.f;   // zero pad for batch-16 scan
        for (int m = tid; m < MTOK; m += 256) {
            lo[b*MTOK+m] = T_; hi[b*MTOK+m] = 0;
            h_sumsq[b*MTOK+m] = 0.f;         // zero for cif-epilogue atomics
        }
        if (tid == 0) lo[b*MTOK] = 0;
        __syncthreads();

        // phase 2: serial carry chain (lane 0), batch-16 double-buffered LDS
        // loads (hides ~120cy ds_read latency) + 2-op dep chain:
        // integ' = sx - floor(sx)  ==bitwise==  (sx>=1 ? sx-1 : sx) for sx in [0,2)
        if (tid == 0) {
            float integ = 0.f;
            float4 c0 = *(const float4*)&al[0];
            float4 c1 = *(const float4*)&al[4];
            float4 c2 = *(const float4*)&al[8];
            float4 c3 = *(const float4*)&al[12];
            for (int t = 0; t < TPAD; t += 16) {
                float4 n0, n1, n2, n3;
                if (t + 16 < TPAD) {
                    n0 = *(const float4*)&al[t+16];
                    n1 = *(const float4*)&al[t+20];
                    n2 = *(const float4*)&al[t+24];
                    n3 = *(const float4*)&al[t+28];
                }
                float4 o0, o1, o2, o3;
                float sx;
                o0.x = integ; sx = integ + c0.x; integ = sx - floorf(sx);
                o0.y = integ; sx = integ + c0.y; integ = sx - floorf(sx);
                o0.z = integ; sx = integ + c0.z; integ = sx - floorf(sx);
                o0.w = integ; sx = integ + c0.w; integ = sx - floorf(sx);
                o1.x = integ; sx = integ + c1.x; integ = sx - floorf(sx);
                o1.y = integ; sx = integ + c1.y; integ = sx - floorf(sx);
                o1.z = integ; sx = integ + c1.z; integ = sx - floorf(sx);
                o1.w = integ; sx = integ + c1.w; integ = sx - floorf(sx);
                o2.x = integ; sx = integ + c2.x; integ = sx - floorf(sx);
                o2.y = integ; sx = integ + c2.y; integ = sx - floorf(sx);
                o2.z = integ; sx = integ + c2.z; integ = sx - floorf(sx);
                o2.w = integ; sx = integ + c2.w; integ = sx - floorf(sx);
                o3.x = integ; sx = integ + c3.x; integ = sx - floorf(sx);
                o3.y = integ; sx = integ + c3.y; integ = sx - floorf(sx);
                o3.z = integ; sx = integ + c3.z; integ = sx - floorf(sx);
                o3.w = integ; sx = integ + c3.w; integ = sx - floorf(sx);
                *(float4*)&ip[t+0]  = o0;
                *(float4*)&ip[t+4]  = o1;
                *(float4*)&ip[t+8]  = o2;
                *(float4*)&ip[t+12] = o3;
                c0 = n0; c1 = n1; c2 = n2; c3 = n3;
            }
        }
        __syncthreads();

        // phase 3: parallel post-pass
        const int t0 = tid * 6;
        const int nm1 = num_tokens[b] - 1;
        int fires[6];
        int cnt = 0;
        if (t0 < T_) {
            #pragma unroll
            for (int j = 0; j < 6; ++j) {
                int t = t0 + j;
                float sx = ip[t] + al[t];     // same fp32 add as serial scan
                fires[j] = (sx >= 1.f) ? 1 : 0;
                cnt += fires[j];
            }
        }
        redI[tid] = cnt; __syncthreads();
        #pragma unroll
        for (int off = 1; off < 256; off <<= 1) {
            int v = redI[tid];
            if (tid >= off) v += redI[tid - off];
            __syncthreads();
            redI[tid] = v;
            __syncthreads();
        }
        if (t0 < T_) {
            int F = redI[tid] - cnt;
            const int base = b*T_;
            #pragma unroll
            for (int j = 0; j < 6; ++j) {
                int t = t0 + j;
                float a = al[t], ipv = ip[t];
                int fire = fires[j];
                F += fire;
                int tk1 = min(F, nm1);
                int tk0 = min(F - fire, nm1);
                float w0 = fire ? (1.f - ipv) : a;
                float w1 = (t < T_-1) ? (a - w0) : 0.f;
                tok0[base+t] = tk0;  w0a[base+t] = w0;
                tok1[base+t] = tk1;  w1a[base+t] = w1;
                if (tk1 != tk0) {
                    hi[b*MTOK + tk0] = t + 1;
                    lo[b*MTOK + tk1] = t;
                }
                if (t == T_-1) hi[b*MTOK + tk1] = T_;
            }
        }
    } else {
        // ================= transpose branch =================
        float (*tile)[33] = (float(*)[33])smem;
        int blk = blockIdx.x - B_;
        const float* src; u16* dst; int R, C, bx, by; bool scaled;
        if (blk < 1600) { src = cif_w;  dst = cwt; R = HM1; C = H_;   bx = blk % 40;  by = blk / 40;  scaled = false; }
        else { blk -= 1600; src = text_w; dst = twt; R = H_;  C = OUT_; bx = blk % 128; by = blk / 128; scaled = true; }
        int c0 = bx * 32, r0 = by * 32;
        int lx = tid & 31, ly = tid >> 5;  // 32 x 8
        #pragma unroll
        for (int j = 0; j < 4; ++j) {
            int r = r0 + ly + j*8;
            tile[ly + j*8][lx] = (r < R) ? src[(size_t)r*C + c0 + lx] : 0.f;
        }
        __syncthreads();
        // write value = src[r0+lx][c0+ly+j*8]; its k-index is r0+lx -> fold rms_w
        float rw = scaled ? rms_w[r0 + lx] : 1.f;
        #pragma unroll
        for (int j = 0; j < 4; ++j) {
            int c = c0 + ly + j*8;
            dst[(size_t)c*KPAD + r0 + lx] = f2bf(tile[lx][ly + j*8] * rw);
        }
    }
}

// K3: sparse pooling -> h1b bf16 [MROWS][KPAD], col 1279 = 0.
// Latency-optimized: weights staged to LDS, branchless float4 main loop.
__global__ __launch_bounds__(256) void k3_pool(
    const float* __restrict__ audio,
    const int* __restrict__ tok0, const float* __restrict__ w0a,
    const int* __restrict__ tok1, const float* __restrict__ w1a,
    const int* __restrict__ lo, const int* __restrict__ hi,
    u16* __restrict__ h1b)
{
    __shared__ float wl[1536];
    const int bm = blockIdx.x;
    const int b = bm / MTOK, m = bm % MTOK;
    const int l = lo[bm], h = hi[bm];
    const int tid = threadIdx.x;
    const int len = h - l;

    // stage combined weights (coalesced; removes scalar-load latency from loop)
    for (int j = tid; j < len; j += 256) {
        int i0 = b*T_ + l + j;
        float w = 0.f;
        if (tok0[i0] == m) w += w0a[i0];
        if (tok1[i0] == m) w += w1a[i0];
        wl[j] = w;
    }
    __syncthreads();

    const int d4 = tid * 4;          // covers 0..1023
    const int d1 = 1024 + tid;       // covers 1024..1279
    const float* rowp = audio + (size_t)(b*T_ + l) * H_;
    float4 acc4 = make_float4(0.f, 0.f, 0.f, 0.f);
    float acc1 = 0.f;
    #pragma unroll 4
    for (int j = 0; j < len; ++j) {
        float w = wl[j];
        const float* row = rowp + (size_t)j * H_;
        float4 r4 = *(const float4*)(row + d4);     // aligned: row stride 5120 B
        float r1 = (d1 < HM1) ? row[d1] : 0.f;
        acc4.x += w * r4.x; acc4.y += w * r4.y;
        acc4.z += w * r4.z; acc4.w += w * r4.w;
        acc1 += w * r1;
    }
    u16* dst = h1b + (size_t)bm * KPAD;
    ushort4 o;
    o.x = f2bf(acc4.x); o.y = f2bf(acc4.y); o.z = f2bf(acc4.z); o.w = f2bf(acc4.w);
    *(ushort4*)&dst[d4] = o;
    dst[d1] = (d1 < HM1) ? f2bf(acc1) : (u16)0;     // d1==1279 -> zero pad
}

// ============================================================================
// 256x256 MFMA bf16 GEMM (B^T form), BK=64, 8 waves, m201-style 8-PHASE
// schedule with counted vmcnt (T3+T4) + setprio (T5).
// Per iteration = 2 K-tiles (even tile in buf0, odd in buf1). Each phase:
//   barrier -> ds_read one operand-half (regs used 1-7 phases later)
//           -> stage one half-tile (global_load_lds, never drained to 0)
//           -> 16 MFMA (one C-quadrant x K=64) under setprio(1)
//           -> lgkmcnt(0)  (pins this phase's LDS reads before next barrier)
// WAR: each stage lands one barrier after its region's last ds_read drains.
// RAW: vmcnt(2)@P3 retires prev-iter P7 stages; vmcnt(4)@P7 retires S4 (P5).
// LDS: linear dest + pre-swizzled global source chunk c=(idx&7)^(row&7);
// read-side applies same XOR -> 0 bank conflicts (measured round 3).
// ============================================================================
#define BAR()     __builtin_amdgcn_s_barrier()
#define LGKM0()   asm volatile("s_waitcnt lgkmcnt(0)" ::: "memory")
#define WAITVM(N) asm volatile("s_waitcnt vmcnt(" #N ")" ::: "memory")

#define LDA_(D, BUF, HH) do { \
  _Pragma("unroll") for (int m_ = 0; m_ < 4; ++m_) { \
    D[m_][0] = *(const bf16x8*)&sA[BUF][aBase + (HH)*4096 + m_*1024 + csw]; \
    D[m_][1] = *(const bf16x8*)&sA[BUF][aBase + (HH)*4096 + m_*1024 + (csw ^ 32)]; \
  } } while (0)

#define LDB_(D, BUF, HH) do { \
  _Pragma("unroll") for (int n_ = 0; n_ < 2; ++n_) { \
    D[n_][0] = *(const bf16x8*)&sB[BUF][bBase + (HH)*2048 + n_*1024 + csw]; \
    D[n_][1] = *(const bf16x8*)&sB[BUF][bBase + (HH)*2048 + n_*1024 + (csw ^ 32)]; \
  } } while (0)

#define STG_A(BUF, HH, KT) do { int kt_ = min((int)(KT), NT-1) * 64; \
  glds16(A + aOff[HH][0] + kt_, &sA[BUF][(HH)*8192 + idx0*8]); \
  glds16(A + aOff[HH][1] + kt_, &sA[BUF][(HH)*8192 + idx1*8]); } while (0)

#define STG_B(BUF, HH, KT) do { int kt_ = min((int)(KT), NT-1) * 64; \
  glds16(Bt + bOff[HH][0] + kt_, &sB[BUF][(HH)*8192 + idx0*8]); \
  glds16(Bt + bOff[HH][1] + kt_, &sB[BUF][(HH)*8192 + idx1*8]); } while (0)

#define MMQ(RA, RB, HA, HB) do { \
  __builtin_amdgcn_s_setprio(1); \
  _Pragma("unroll") for (int m_ = 0; m_ < 4; ++m_) \
  _Pragma("unroll") for (int n_ = 0; n_ < 2; ++n_) \
  _Pragma("unroll") for (int k_ = 0; k_ < 2; ++k_) \
    acc[(HA)*4+m_][(HB)*2+n_] = __builtin_amdgcn_mfma_f32_16x16x32_bf16( \
        RA[m_][k_], RB[n_][k_], acc[(HA)*4+m_][(HB)*2+n_], 0, 0, 0); \
  __builtin_amdgcn_s_setprio(0); \
} while (0)

template<bool CIF>
__global__ __launch_bounds__(512, 2) void gemm256(
    const u16* __restrict__ A, const u16* __restrict__ Bt,
    const float* __restrict__ bias, void* __restrict__ Cv,
    float* __restrict__ h_sumsq, int M, int N)
{
    constexpr int K = KPAD;          // 1280
    constexpr int NT = K / 64;       // 20 K-tiles
    constexpr int NIT = NT / 2;      // 10 iterations (2 tiles each)
    __shared__ u16 sA[2][16384];     // [buf][256 rows x 64]  (32 KB each)
    __shared__ u16 sB[2][16384];     // total LDS 128 KB
    const int tid = threadIdx.x;
    const int wave = tid >> 6, lane = tid & 63;
    const int wr = wave >> 2, wc = wave & 3;       // 2 x 4 wave grid
    const int lrow = lane & 15, quad = lane >> 4;
    const int m0 = blockIdx.y * 256, n0 = blockIdx.x * 256;

    // staging maps: 2 loads/thread per 16KB half-tile (128 rows x 64)
    const int idx0 = tid, idx1 = tid + 512;
    const int rS0 = idx0 >> 3, rS1 = idx1 >> 3;
    const int cG0 = ((idx0 & 7) ^ (rS0 & 7)) * 8;
    const int cG1 = ((idx1 & 7) ^ (rS1 & 7)) * 8;
    u32 aOff[2][2], bOff[2][2];
    #pragma unroll
    for (int h = 0; h < 2; ++h) {
        aOff[h][0] = (u32)min(m0 + h*128 + rS0, M-1) * K + cG0;
        aOff[h][1] = (u32)min(m0 + h*128 + rS1, M-1) * K + cG1;
        bOff[h][0] = (u32)(n0 + h*128 + rS0) * K + cG0;
        bOff[h][1] = (u32)(n0 + h*128 + rS1) * K + cG1;
    }
    // fragment read bases (element offsets); phys chunk = logical ^ (row&7)
    const int csw = (quad ^ (lrow & 7)) << 3;
    const int aBase = (wr*128 + lrow) * 64;
    const int bBase = (wc*64 + lrow) * 64;

    bf16x8 rA0[4][2], rA1[4][2];     // wave A-halves (mi 0-3 / 4-7) x ks
    bf16x8 rB0[2][2], rB1[2][2];     // wave B-halves (ni 0-1 / 2-3) x ks
    f32x4 acc[8][4] = {};

    // ---- prologue: stage tile0 -> buf0, tile1 -> buf1 (16 loads) ----
    STG_A(0,0,0); STG_A(0,1,0); STG_B(0,0,0); STG_B(0,1,0);
    STG_A(1,0,1); STG_A(1,1,1); STG_B(1,0,1); STG_B(1,1,1);
    WAITVM(8);                      // retire tile0's 8 loads; tile1 in flight
    BAR();
    LDA_(rA0, 0, 0);                // A0(t0)
    LDB_(rB0, 0, 0);                // B0(t0)
    LGKM0();

    for (int it = 0; it < NIT; ++it) {
        const int t = it * 2;
        // P1: read A1(t)                          mma Q(A0,B0) t
        BAR(); LDA_(rA1, 0, 1);
        MMQ(rA0, rB0, 0, 0); LGKM0();
        // P2: read B1(t); stage t+2.A-lo          mma Q(A1,B0) t
        BAR(); LDB_(rB1, 0, 1); STG_A(0, 0, t+2);
        MMQ(rA1, rB0, 1, 0); LGKM0();
        // P3: [vmcnt(2)] read B0(t+1); stage t+2.A-up   mma Q(A0,B1) t
        WAITVM(2); BAR(); LDB_(rB0, 1, 0); STG_A(0, 1, t+2);
        MMQ(rA0, rB1, 0, 1); LGKM0();
        // P4: read A0(t+1); stage t+2.B-lo        mma Q(A1,B1) t
        BAR(); LDA_(rA0, 1, 0); STG_B(0, 0, t+2);
        MMQ(rA1, rB1, 1, 1); LGKM0();
        // P5: read A1(t+1); stage t+2.B-up        mma Q(A0,B0) t+1
        BAR(); LDA_(rA1, 1, 1); STG_B(0, 1, t+2);
        MMQ(rA0, rB0, 0, 0); LGKM0();
        // P6: read B1(t+1); stage t+3.A-lo,A-up   mma Q(A1,B0) t+1
        BAR(); LDB_(rB1, 1, 1); STG_A(1, 0, t+3); STG_A(1, 1, t+3);
        MMQ(rA1, rB0, 1, 0); LGKM0();
        // P7: [vmcnt(4)] read B0(t+2); stage t+3.B-lo,B-up   mma Q(A0,B1) t+1
        WAITVM(4); BAR(); LDB_(rB0, 0, 0); STG_B(1, 0, t+3); STG_B(1, 1, t+3);
        MMQ(rA0, rB1, 0, 1); LGKM0();
        // P8: read A0(t+2)                        mma Q(A1,B1) t+1
        BAR(); LDA_(rA0, 0, 0);
        MMQ(rA1, rB1, 1, 1); LGKM0();
    }

    // epilogue: C/D layout col=lane&15 (n), row=quad*4+rr (m)
    float bv[4];
    #pragma unroll
    for (int ni = 0; ni < 4; ++ni)
        bv[ni] = bias[n0 + wc*64 + ni*16 + lrow];

    #pragma unroll
    for (int mi = 0; mi < 8; ++mi) {
        #pragma unroll
        for (int rr = 0; rr < 4; ++rr) {
            int row = m0 + wr*128 + mi*16 + quad*4 + rr;
            if (CIF) {
                float ss = 0.f;
                #pragma unroll
                for (int ni = 0; ni < 4; ++ni) {
                    float v = acc[mi][ni][rr] + bv[ni];
                    ss += v * v;
                    if (row < M)
                        ((u16*)Cv)[(size_t)row*N + (n0 + wc*64 + ni*16 + lrow)] = f2bf(v);
                }
                // reduce ss over the 16 lanes (lrow) sharing this row
                ss += __shfl_xor(ss, 1);
                ss += __shfl_xor(ss, 2);
                ss += __shfl_xor(ss, 4);
                ss += __shfl_xor(ss, 8);
                if (lrow == 0 && row < M) atomicAdd(&h_sumsq[row], ss);
            } else {
                float inv = 1.f;
                if (row < M)
                    inv = 1.f / sqrtf(h_sumsq[row] / (float)H_ + 1e-6f);
                #pragma unroll
                for (int ni = 0; ni < 4; ++ni) {
                    if (row < M)
                        ((float*)Cv)[(size_t)row*N + (n0 + wc*64 + ni*16 + lrow)] =
                            acc[mi][ni][rr] * inv + bv[ni];
                }
            }
        }
    }
}

extern "C" void kernel_launch(void* const* d_in, const int* in_sizes, int n_in,
                              void* d_out, int out_size, void* d_ws, size_t ws_size,
                              hipStream_t stream) {
    (void)in_sizes; (void)n_in; (void)out_size; (void)ws_size;
    const float* audio      = (const float*)d_in[0];
    const int*   num_tokens = (const int*)d_in[1];
    const float* rms_w      = (const float*)d_in[2];
    const float* cif_w      = (const float*)d_in[3];
    const float* cif_b      = (const float*)d_in[4];
    const float* text_w     = (const float*)d_in[5];
    const float* text_b     = (const float*)d_in[6];

    float* out  = (float*)d_out;                   // fp32 output
    float* pred = out + (size_t)MROWS * OUT_;      // pred_num_tokens tail (8 floats)

    char* ws = (char*)d_ws;
    float* h_sumsq = (float*)(ws + 0);         // 12000 B (zeroed in k_front)
    float* w0a  = (float*)(ws + 48000);
    float* w1a  = (float*)(ws + 96000);
    int*   tok0 = (int*)  (ws + 144000);
    int*   tok1 = (int*)  (ws + 192000);
    int*   lo   = (int*)  (ws + 240000);
    int*   hi   = (int*)  (ws + 252000);
    // DISJOINT regions (no lifetime aliasing):
    u16* h1b = (u16*)(ws + 264192);     //  7,680,000 B
    u16* cwt = (u16*)(ws + 7944192);    //  3,276,800 B
    u16* twt = (u16*)(ws + 11220992);   // 10,485,760 B  (rms_w folded in)
    u16* hX  = (u16*)(ws + 21706752);   //  7,680,000 B  (cif out, unnormalized)
    // total ws usage: 29,386,752 B

    // scan (blocks 0..7) + weight transposes (blocks 8..6727)
    k_front<<<B_ + 1600 + 5120, 256, 0, stream>>>(
        audio, num_tokens, rms_w, pred, tok0, w0a, tok1, w1a, lo, hi,
        h_sumsq, cif_w, text_w, cwt, twt);
    k3_pool<<<MROWS, 256, 0, stream>>>(audio, tok0, w0a, tok1, w1a, lo, hi, h1b);
    // cif_proj (bf16 out + row sumsq): hX = h1b . cwt^T + cif_b
    gemm256<true><<<dim3(H_/256, (MROWS+255)/256), 512, 0, stream>>>(
        h1b, cwt, cif_b, hX, h_sumsq, MROWS, H_);
    // text_proj (fp32 out, 1/rms applied in epilogue): out = norm(hX) . twt^T + text_b
    gemm256<false><<<dim3(OUT_/256, (MROWS+255)/256), 512, 0, stream>>>(
        hX, twt, text_b, out, h_sumsq, MROWS, OUT_);
}

// Round 5
// 263.500 us; speedup vs baseline: 1.2068x; 1.2068x over previous
//
#include <hip/hip_runtime.h>
#include <hip/hip_bf16.h>
#include <stdint.h>

// Problem constants (from reference)
#define B_ 8
#define T_ 1500
#define TPAD 1504         // T_ padded to multiple of 16 for the scan batcher
#define H_ 1280
#define HM1 1279
#define OUT_ 4096
#define MTOK 375
#define MROWS (B_*MTOK)   // 3000
#define KPAD 1280         // shared K for both GEMMs (cif K=1279 zero-padded)

typedef __attribute__((ext_vector_type(8))) short bf16x8;  // 8 bf16 = 4 VGPRs
typedef __attribute__((ext_vector_type(4))) float f32x4;
typedef unsigned short u16;
typedef unsigned int u32;

static __device__ __forceinline__ u16 f2bf(float f) {
    unsigned int x = __float_as_uint(f);
    unsigned int r = (x + 0x7fffu + ((x >> 16) & 1u)) >> 16;
    return (u16)r;
}
static __device__ __forceinline__ void glds16(const u16* g, u16* l) {
    __builtin_amdgcn_global_load_lds(
        (const __attribute__((address_space(1))) void*)g,
        (__attribute__((address_space(3))) void*)l, 16, 0, 0);
}

// Front kernel: blocks 0..7 = fused sigmoid+scan+post-pass (one per batch);
// blocks 8.. = both weight transposes (text transpose folds in rms_w).
__global__ __launch_bounds__(256) void k_front(
    const float* __restrict__ audio, const int* __restrict__ num_tokens,
    const float* __restrict__ rms_w,
    float* __restrict__ pred_out,
    int* __restrict__ tok0, float* __restrict__ w0a,
    int* __restrict__ tok1, float* __restrict__ w1a,
    int* __restrict__ lo, int* __restrict__ hi,
    float* __restrict__ h_sumsq,
    const float* __restrict__ cif_w, const float* __restrict__ text_w,
    u16* __restrict__ cwt, u16* __restrict__ twt)
{
    __shared__ float smem[3524];   // union: scan(3521 floats) / transpose tile(32x33)
    const int tid = threadIdx.x;

    if (blockIdx.x < B_) {
        // ================= CIF scan branch =================
        const int b = blockIdx.x;
        float* al = smem;                    // [1504] (1500 + 4 zero pad)
        float* ip = smem + TPAD;             // [1504]
        float* red = smem + 2*TPAD;          // [256]
        int*   redI = (int*)(smem + 2*TPAD + 256);   // [256]
        float* scale_sh = smem + 2*TPAD + 512;

        // phase 1: sigmoid + pred + scale
        float sig[6];
        float s = 0.f;
        #pragma unroll
        for (int i = 0; i < 6; ++i) {
            int t = tid + i*256;
            sig[i] = 0.f;
            if (t < T_) {
                float x = audio[((size_t)b*T_ + t)*H_ + (H_-1)];
                sig[i] = 1.f / (1.f + expf(-x));
                s += sig[i];
            }
        }
        red[tid] = s; __syncthreads();
        for (int off = 128; off > 0; off >>= 1) {
            if (tid < off) red[tid] += red[tid+off];
            __syncthreads();
        }
        if (tid == 0) {
            float pred = red[0];
            pred_out[b] = pred;
            *scale_sh = (float)num_tokens[b] / pred;
        }
        __syncthreads();
        float scale = *scale_sh;
        #pragma unroll
        for (int i = 0; i < 6; ++i) {
            int t = tid + i*256;
            if (t < T_) al[t] = sig[i] * scale;
        }
        if (tid < TPAD - T_) al[T_ + tid] = 0.f;   // zero pad for batch-16 scan
        for (int m = tid; m < MTOK; m += 256) {
            lo[b*MTOK+m] = T_; hi[b*MTOK+m] = 0;
            h_sumsq[b*MTOK+m] = 0.f;         // zero for cif-epilogue atomics
        }
        if (tid == 0) lo[b*MTOK] = 0;
        __syncthreads();

        // phase 2: serial carry chain (lane 0), batch-16 double-buffered LDS
        // loads (hides ~120cy ds_read latency) + 2-op dep chain:
        // integ' = sx - floor(sx)  ==bitwise==  (sx>=1 ? sx-1 : sx) for sx in [0,2)
        if (tid == 0) {
            float integ = 0.f;
            float4 c0 = *(const float4*)&al[0];
            float4 c1 = *(const float4*)&al[4];
            float4 c2 = *(const float4*)&al[8];
            float4 c3 = *(const float4*)&al[12];
            for (int t = 0; t < TPAD; t += 16) {
                float4 n0, n1, n2, n3;
                if (t + 16 < TPAD) {
                    n0 = *(const float4*)&al[t+16];
                    n1 = *(const float4*)&al[t+20];
                    n2 = *(const float4*)&al[t+24];
                    n3 = *(const float4*)&al[t+28];
                }
                float4 o0, o1, o2, o3;
                float sx;
                o0.x = integ; sx = integ + c0.x; integ = sx - floorf(sx);
                o0.y = integ; sx = integ + c0.y; integ = sx - floorf(sx);
                o0.z = integ; sx = integ + c0.z; integ = sx - floorf(sx);
                o0.w = integ; sx = integ + c0.w; integ = sx - floorf(sx);
                o1.x = integ; sx = integ + c1.x; integ = sx - floorf(sx);
                o1.y = integ; sx = integ + c1.y; integ = sx - floorf(sx);
                o1.z = integ; sx = integ + c1.z; integ = sx - floorf(sx);
                o1.w = integ; sx = integ + c1.w; integ = sx - floorf(sx);
                o2.x = integ; sx = integ + c2.x; integ = sx - floorf(sx);
                o2.y = integ; sx = integ + c2.y; integ = sx - floorf(sx);
                o2.z = integ; sx = integ + c2.z; integ = sx - floorf(sx);
                o2.w = integ; sx = integ + c2.w; integ = sx - floorf(sx);
                o3.x = integ; sx = integ + c3.x; integ = sx - floorf(sx);
                o3.y = integ; sx = integ + c3.y; integ = sx - floorf(sx);
                o3.z = integ; sx = integ + c3.z; integ = sx - floorf(sx);
                o3.w = integ; sx = integ + c3.w; integ = sx - floorf(sx);
                *(float4*)&ip[t+0]  = o0;
                *(float4*)&ip[t+4]  = o1;
                *(float4*)&ip[t+8]  = o2;
                *(float4*)&ip[t+12] = o3;
                c0 = n0; c1 = n1; c2 = n2; c3 = n3;
            }
        }
        __syncthreads();

        // phase 3: parallel post-pass
        const int t0 = tid * 6;
        const int nm1 = num_tokens[b] - 1;
        int fires[6];
        int cnt = 0;
        if (t0 < T_) {
            #pragma unroll
            for (int j = 0; j < 6; ++j) {
                int t = t0 + j;
                float sx = ip[t] + al[t];     // same fp32 add as serial scan
                fires[j] = (sx >= 1.f) ? 1 : 0;
                cnt += fires[j];
            }
        }
        redI[tid] = cnt; __syncthreads();
        #pragma unroll
        for (int off = 1; off < 256; off <<= 1) {
            int v = redI[tid];
            if (tid >= off) v += redI[tid - off];
            __syncthreads();
            redI[tid] = v;
            __syncthreads();
        }
        if (t0 < T_) {
            int F = redI[tid] - cnt;
            const int base = b*T_;
            #pragma unroll
            for (int j = 0; j < 6; ++j) {
                int t = t0 + j;
                float a = al[t], ipv = ip[t];
                int fire = fires[j];
                F += fire;
                int tk1 = min(F, nm1);
                int tk0 = min(F - fire, nm1);
                float w0 = fire ? (1.f - ipv) : a;
                float w1 = (t < T_-1) ? (a - w0) : 0.f;
                tok0[base+t] = tk0;  w0a[base+t] = w0;
                tok1[base+t] = tk1;  w1a[base+t] = w1;
                if (tk1 != tk0) {
                    hi[b*MTOK + tk0] = t + 1;
                    lo[b*MTOK + tk1] = t;
                }
                if (t == T_-1) hi[b*MTOK + tk1] = T_;
            }
        }
    } else {
        // ================= transpose branch =================
        float (*tile)[33] = (float(*)[33])smem;
        int blk = blockIdx.x - B_;
        const float* src; u16* dst; int R, C, bx, by; bool scaled;
        if (blk < 1600) { src = cif_w;  dst = cwt; R = HM1; C = H_;   bx = blk % 40;  by = blk / 40;  scaled = false; }
        else { blk -= 1600; src = text_w; dst = twt; R = H_;  C = OUT_; bx = blk % 128; by = blk / 128; scaled = true; }
        int c0 = bx * 32, r0 = by * 32;
        int lx = tid & 31, ly = tid >> 5;  // 32 x 8
        #pragma unroll
        for (int j = 0; j < 4; ++j) {
            int r = r0 + ly + j*8;
            tile[ly + j*8][lx] = (r < R) ? src[(size_t)r*C + c0 + lx] : 0.f;
        }
        __syncthreads();
        // write value = src[r0+lx][c0+ly+j*8]; its k-index is r0+lx -> fold rms_w
        float rw = scaled ? rms_w[r0 + lx] : 1.f;
        #pragma unroll
        for (int j = 0; j < 4; ++j) {
            int c = c0 + ly + j*8;
            dst[(size_t)c*KPAD + r0 + lx] = f2bf(tile[lx][ly + j*8] * rw);
        }
    }
}

// K3: sparse pooling -> h1b bf16 [MROWS][KPAD], col 1279 = 0.
// Latency-optimized: weights staged to LDS, branchless float4 main loop.
__global__ __launch_bounds__(256) void k3_pool(
    const float* __restrict__ audio,
    const int* __restrict__ tok0, const float* __restrict__ w0a,
    const int* __restrict__ tok1, const float* __restrict__ w1a,
    const int* __restrict__ lo, const int* __restrict__ hi,
    u16* __restrict__ h1b)
{
    __shared__ float wl[1536];
    const int bm = blockIdx.x;
    const int b = bm / MTOK, m = bm % MTOK;
    const int l = lo[bm], h = hi[bm];
    const int tid = threadIdx.x;
    const int len = h - l;

    // stage combined weights (coalesced; removes scalar-load latency from loop)
    for (int j = tid; j < len; j += 256) {
        int i0 = b*T_ + l + j;
        float w = 0.f;
        if (tok0[i0] == m) w += w0a[i0];
        if (tok1[i0] == m) w += w1a[i0];
        wl[j] = w;
    }
    __syncthreads();

    const int d4 = tid * 4;          // covers 0..1023
    const int d1 = 1024 + tid;       // covers 1024..1279
    const float* rowp = audio + (size_t)(b*T_ + l) * H_;
    float4 acc4 = make_float4(0.f, 0.f, 0.f, 0.f);
    float acc1 = 0.f;
    #pragma unroll 4
    for (int j = 0; j < len; ++j) {
        float w = wl[j];
        const float* row = rowp + (size_t)j * H_;
        float4 r4 = *(const float4*)(row + d4);     // aligned: row stride 5120 B
        float r1 = (d1 < HM1) ? row[d1] : 0.f;
        acc4.x += w * r4.x; acc4.y += w * r4.y;
        acc4.z += w * r4.z; acc4.w += w * r4.w;
        acc1 += w * r1;
    }
    u16* dst = h1b + (size_t)bm * KPAD;
    ushort4 o;
    o.x = f2bf(acc4.x); o.y = f2bf(acc4.y); o.z = f2bf(acc4.z); o.w = f2bf(acc4.w);
    *(ushort4*)&dst[d4] = o;
    dst[d1] = (d1 < HM1) ? f2bf(acc1) : (u16)0;     // d1==1279 -> zero pad
}

// ============================================================================
// 256x256 MFMA bf16 GEMM (B^T form), BK=64, 8 waves, m201-faithful 8-phase.
// Per phase: {ds_read THIS phase's subtile; stage 1 half-tile; BAR;
//   lgkmcnt(0)+sched_barrier(0); setprio(1) 16 MFMA setprio(0); BAR}.
// Serpentine quadrants Q00->Q01->Q11->Q10 => 1 A-set + 1 B-set live
// (48 frag VGPRs; acc=128 AGPR; total ~90 arch VGPR -- NO spills, the
// round-4 failure mode).  Double barrier per phase makes per-phase staging
// WAR-safe (stage issued >=1 closing-barrier after region's last pinned read).
// Stage ledger (iter: tiles t=buf0 read P1-P4, t+1=buf1 read P5-P8):
//   P1:b1.Blo<-t+1  P2:b1.Bup<-t+1  P4:b0.Alo<-t+2  P5:b0.Aup<-t+2
//   P6:b0.Blo<-t+2  P7:b0.Bup<-t+2  P8:b1.Alo,Aup<-t+3
// Counted waits (never 0 in-loop): vmcnt(2) end-P4 (retires prev-P8 b1.A +
// P1/P2 b1.B; keeps P4's stage), vmcnt(4) end-P8 (retires b0's 4 stages).
// LDS: linear dest + pre-swizzled global source chunk c=(idx&7)^(row&7);
// read-side same XOR -> 0 bank conflicts (measured round 3).
// ============================================================================
#define BAR()     __builtin_amdgcn_s_barrier()
#define MEMF()    asm volatile("" ::: "memory")
#define LGKM0()   asm volatile("s_waitcnt lgkmcnt(0)" ::: "memory")
#define LGKM8()   asm volatile("s_waitcnt lgkmcnt(8)" ::: "memory")
#define WAITVM(N) asm volatile("s_waitcnt vmcnt(" #N ")" ::: "memory")
#define SB0()     __builtin_amdgcn_sched_barrier(0)
#define PRIO1()   __builtin_amdgcn_s_setprio(1)
#define PRIO0()   __builtin_amdgcn_s_setprio(0)

// fragment reads: quadrant HA of A (4 mi x 2 ks), HB of B (2 ni x 2 ks)
#define RD_A(BUF, HA) do { \
  _Pragma("unroll") for (int m_ = 0; m_ < 4; ++m_) { \
    fA[m_][0] = *(const bf16x8*)&sA[BUF][aBase + (HA)*4096 + m_*1024 + csw]; \
    fA[m_][1] = *(const bf16x8*)&sA[BUF][aBase + (HA)*4096 + m_*1024 + (csw ^ 32)]; \
  } } while (0)

#define RD_B(BUF, HB) do { \
  _Pragma("unroll") for (int n_ = 0; n_ < 2; ++n_) { \
    fB[n_][0] = *(const bf16x8*)&sB[BUF][bBase + (HB)*2048 + n_*1024 + csw]; \
    fB[n_][1] = *(const bf16x8*)&sB[BUF][bBase + (HB)*2048 + n_*1024 + (csw ^ 32)]; \
  } } while (0)

// stage half-tile HH (128 rows) of buffer BUF from K-tile KT (2 glds/thread)
#define STG_A(BUF, HH, KT) do { int kt_ = min((int)(KT), NT-1) * 64; \
  glds16(A + aOff[HH][0] + kt_, &sA[BUF][(HH)*8192 + idx0*8]); \
  glds16(A + aOff[HH][1] + kt_, &sA[BUF][(HH)*8192 + idx1*8]); } while (0)

#define STG_B(BUF, HH, KT) do { int kt_ = min((int)(KT), NT-1) * 64; \
  glds16(Bt + bOff[HH][0] + kt_, &sB[BUF][(HH)*8192 + idx0*8]); \
  glds16(Bt + bOff[HH][1] + kt_, &sB[BUF][(HH)*8192 + idx1*8]); } while (0)

// 16 MFMA: quadrant (HA,HB) over K=64 (2 ks)
#define MMQ(HA, HB) do { \
  PRIO1(); \
  _Pragma("unroll") for (int m_ = 0; m_ < 4; ++m_) \
  _Pragma("unroll") for (int n_ = 0; n_ < 2; ++n_) \
  _Pragma("unroll") for (int k_ = 0; k_ < 2; ++k_) \
    acc[(HA)*4+m_][(HB)*2+n_] = __builtin_amdgcn_mfma_f32_16x16x32_bf16( \
        fA[m_][k_], fB[n_][k_], acc[(HA)*4+m_][(HB)*2+n_], 0, 0, 0); \
  PRIO0(); \
} while (0)

template<bool CIF>
__global__ __launch_bounds__(512, 2) void gemm256(
    const u16* __restrict__ A, const u16* __restrict__ Bt,
    const float* __restrict__ bias, void* __restrict__ Cv,
    float* __restrict__ h_sumsq, int M, int N)
{
    constexpr int K = KPAD;          // 1280
    constexpr int NT = K / 64;       // 20 K-tiles
    constexpr int NIT = NT / 2;      // 10 iterations (2 tiles each)
    __shared__ u16 sA[2][16384];     // [buf][256 rows x 64]  (32 KB each)
    __shared__ u16 sB[2][16384];     // total LDS 128 KB
    const int tid = threadIdx.x;
    const int wave = tid >> 6, lane = tid & 63;
    const int wr = wave >> 2, wc = wave & 3;       // 2 x 4 wave grid
    const int lrow = lane & 15, quad = lane >> 4;
    const int m0 = blockIdx.y * 256, n0 = blockIdx.x * 256;

    // staging maps: 2 glds/thread per 16KB half-tile (128 rows x 64)
    const int idx0 = tid, idx1 = tid + 512;
    const int rS0 = idx0 >> 3, rS1 = idx1 >> 3;
    const int cG0 = ((idx0 & 7) ^ (rS0 & 7)) * 8;
    const int cG1 = ((idx1 & 7) ^ (rS1 & 7)) * 8;
    u32 aOff[2][2], bOff[2][2];
    #pragma unroll
    for (int h = 0; h < 2; ++h) {
        aOff[h][0] = (u32)min(m0 + h*128 + rS0, M-1) * K + cG0;
        aOff[h][1] = (u32)min(m0 + h*128 + rS1, M-1) * K + cG1;
        bOff[h][0] = (u32)(n0 + h*128 + rS0) * K + cG0;
        bOff[h][1] = (u32)(n0 + h*128 + rS1) * K + cG1;
    }
    // fragment read bases (element offsets); phys chunk = logical ^ (row&7)
    const int csw = (quad ^ (lrow & 7)) << 3;
    const int aBase = (wr*128 + lrow) * 64;
    const int bBase = (wc*64 + lrow) * 64;

    bf16x8 fA[4][2];                 // current A quadrant (32 VGPR)
    bf16x8 fB[2][2];                 // current B quadrant (16 VGPR)
    f32x4 acc[8][4] = {};            // 128 AGPR

    // ---- prologue: buf0 <- tile0 (A+B), buf1.A <- tile1  (12 glds) ----
    STG_A(0,0,0); STG_A(0,1,0); STG_B(0,0,0); STG_B(0,1,0);
    STG_A(1,0,1); STG_A(1,1,1);
    WAITVM(4);                       // retire buf0's 8; buf1.A stays in flight
    BAR(); MEMF();

    for (int it = 0; it < NIT; ++it) {
        const int t = 2*it;
        // P1: Q(0,0) buf0 | stage b1.Blo <- t+1
        RD_A(0,0); RD_B(0,0);
        STG_B(1,0, t+1);
        LGKM8();
        BAR(); LGKM0(); SB0();
        MMQ(0,0);
        BAR(); MEMF();
        // P2: Q(0,1) buf0 (A held) | stage b1.Bup <- t+1
        RD_B(0,1);
        STG_B(1,1, t+1);
        BAR(); LGKM0(); SB0();
        MMQ(0,1);
        BAR(); MEMF();
        // P3: Q(1,1) buf0 (B held)
        RD_A(0,1);
        BAR(); LGKM0(); SB0();
        MMQ(1,1);
        BAR(); MEMF();
        // P4: Q(1,0) buf0 (A held, B0 re-read) | stage b0.Alo <- t+2 | vmcnt(2)
        RD_B(0,0);
        STG_A(0,0, t+2);
        BAR(); LGKM0(); SB0();
        MMQ(1,0);
        WAITVM(2);
        BAR(); MEMF();
        // P5: Q(0,0) buf1 | stage b0.Aup <- t+2
        RD_A(1,0); RD_B(1,0);
        STG_A(0,1, t+2);
        LGKM8();
        BAR(); LGKM0(); SB0();
        MMQ(0,0);
        BAR(); MEMF();
        // P6: Q(0,1) buf1 | stage b0.Blo <- t+2
        RD_B(1,1);
        STG_B(0,0, t+2);
        BAR(); LGKM0(); SB0();
        MMQ(0,1);
        BAR(); MEMF();
        // P7: Q(1,1) buf1 | stage b0.Bup <- t+2
        RD_A(1,1);
        STG_B(0,1, t+2);
        BAR(); LGKM0(); SB0();
        MMQ(1,1);
        BAR(); MEMF();
        // P8: Q(1,0) buf1 | stage b1.Alo,Aup <- t+3 | vmcnt(4)
        RD_B(1,0);
        STG_A(1,0, t+3); STG_A(1,1, t+3);
        BAR(); LGKM0(); SB0();
        MMQ(1,0);
        WAITVM(4);
        BAR(); MEMF();
    }

    // epilogue: C/D layout col=lane&15 (n), row=quad*4+rr (m)
    float bv[4];
    #pragma unroll
    for (int ni = 0; ni < 4; ++ni)
        bv[ni] = bias[n0 + wc*64 + ni*16 + lrow];

    #pragma unroll
    for (int mi = 0; mi < 8; ++mi) {
        #pragma unroll
        for (int rr = 0; rr < 4; ++rr) {
            int row = m0 + wr*128 + mi*16 + quad*4 + rr;
            if (CIF) {
                float ss = 0.f;
                #pragma unroll
                for (int ni = 0; ni < 4; ++ni) {
                    float v = acc[mi][ni][rr] + bv[ni];
                    ss += v * v;
                    if (row < M)
                        ((u16*)Cv)[(size_t)row*N + (n0 + wc*64 + ni*16 + lrow)] = f2bf(v);
                }
                // reduce ss over the 16 lanes (lrow) sharing this row
                ss += __shfl_xor(ss, 1);
                ss += __shfl_xor(ss, 2);
                ss += __shfl_xor(ss, 4);
                ss += __shfl_xor(ss, 8);
                if (lrow == 0 && row < M) atomicAdd(&h_sumsq[row], ss);
            } else {
                float inv = 1.f;
                if (row < M)
                    inv = 1.f / sqrtf(h_sumsq[row] / (float)H_ + 1e-6f);
                #pragma unroll
                for (int ni = 0; ni < 4; ++ni) {
                    if (row < M)
                        ((float*)Cv)[(size_t)row*N + (n0 + wc*64 + ni*16 + lrow)] =
                            acc[mi][ni][rr] * inv + bv[ni];
                }
            }
        }
    }
}

extern "C" void kernel_launch(void* const* d_in, const int* in_sizes, int n_in,
                              void* d_out, int out_size, void* d_ws, size_t ws_size,
                              hipStream_t stream) {
    (void)in_sizes; (void)n_in; (void)out_size; (void)ws_size;
    const float* audio      = (const float*)d_in[0];
    const int*   num_tokens = (const int*)d_in[1];
    const float* rms_w      = (const float*)d_in[2];
    const float* cif_w      = (const float*)d_in[3];
    const float* cif_b      = (const float*)d_in[4];
    const float* text_w     = (const float*)d_in[5];
    const float* text_b     = (const float*)d_in[6];

    float* out  = (float*)d_out;                   // fp32 output
    float* pred = out + (size_t)MROWS * OUT_;      // pred_num_tokens tail (8 floats)

    char* ws = (char*)d_ws;
    float* h_sumsq = (float*)(ws + 0);         // 12000 B (zeroed in k_front)
    float* w0a  = (float*)(ws + 48000);
    float* w1a  = (float*)(ws + 96000);
    int*   tok0 = (int*)  (ws + 144000);
    int*   tok1 = (int*)  (ws + 192000);
    int*   lo   = (int*)  (ws + 240000);
    int*   hi   = (int*)  (ws + 252000);
    // DISJOINT regions (no lifetime aliasing):
    u16* h1b = (u16*)(ws + 264192);     //  7,680,000 B
    u16* cwt = (u16*)(ws + 7944192);    //  3,276,800 B
    u16* twt = (u16*)(ws + 11220992);   // 10,485,760 B  (rms_w folded in)
    u16* hX  = (u16*)(ws + 21706752);   //  7,680,000 B  (cif out, unnormalized)
    // total ws usage: 29,386,752 B

    // scan (blocks 0..7) + weight transposes (blocks 8..6727)
    k_front<<<B_ + 1600 + 5120, 256, 0, stream>>>(
        audio, num_tokens, rms_w, pred, tok0, w0a, tok1, w1a, lo, hi,
        h_sumsq, cif_w, text_w, cwt, twt);
    k3_pool<<<MROWS, 256, 0, stream>>>(audio, tok0, w0a, tok1, w1a, lo, hi, h1b);
    // cif_proj (bf16 out + row sumsq): hX = h1b . cwt^T + cif_b
    gemm256<true><<<dim3(H_/256, (MROWS+255)/256), 512, 0, stream>>>(
        h1b, cwt, cif_b, hX, h_sumsq, MROWS, H_);
    // text_proj (fp32 out, 1/rms applied in epilogue): out = norm(hX) . twt^T + text_b
    gemm256<false><<<dim3(OUT_/256, (MROWS+255)/256), 512, 0, stream>>>(
        hX, twt, text_b, out, h_sumsq, MROWS, OUT_);
}

// Round 6
// 239.045 us; speedup vs baseline: 1.3303x; 1.1023x over previous
//
#include <hip/hip_runtime.h>
#include <hip/hip_bf16.h>
#include <stdint.h>

// Problem constants (from reference)
#define B_ 8
#define T_ 1500
#define TPAD 1504         // T_ padded to multiple of 16 for the scan batcher
#define H_ 1280
#define HM1 1279
#define OUT_ 4096
#define MTOK 375
#define MROWS (B_*MTOK)   // 3000
#define KPAD 1280         // shared K for both GEMMs (cif K=1279 zero-padded)

typedef __attribute__((ext_vector_type(8))) short bf16x8;  // 8 bf16 = 4 VGPRs
typedef __attribute__((ext_vector_type(4))) float f32x4;
typedef unsigned short u16;

static __device__ __forceinline__ u16 f2bf(float f) {
    unsigned int x = __float_as_uint(f);
    unsigned int r = (x + 0x7fffu + ((x >> 16) & 1u)) >> 16;
    return (u16)r;
}
static __device__ __forceinline__ void glds16(const u16* g, u16* l) {
    __builtin_amdgcn_global_load_lds(
        (const __attribute__((address_space(1))) void*)g,
        (__attribute__((address_space(3))) void*)l, 16, 0, 0);
}

// Front kernel: blocks 0..7 = fused sigmoid+scan+post-pass (one per batch);
// blocks 8.. = both weight transposes (text transpose folds in rms_w).
__global__ __launch_bounds__(256) void k_front(
    const float* __restrict__ audio, const int* __restrict__ num_tokens,
    const float* __restrict__ rms_w,
    float* __restrict__ pred_out,
    int* __restrict__ tok0, float* __restrict__ w0a,
    int* __restrict__ tok1, float* __restrict__ w1a,
    int* __restrict__ lo, int* __restrict__ hi,
    float* __restrict__ h_sumsq,
    const float* __restrict__ cif_w, const float* __restrict__ text_w,
    u16* __restrict__ cwt, u16* __restrict__ twt)
{
    __shared__ float smem[3524];   // union: scan(3521 floats) / transpose tile(32x33)
    const int tid = threadIdx.x;

    if (blockIdx.x < B_) {
        // ================= CIF scan branch =================
        const int b = blockIdx.x;
        float* al = smem;                    // [1504] (1500 + 4 zero pad)
        float* ip = smem + TPAD;             // [1504]
        float* red = smem + 2*TPAD;          // [256]
        int*   redI = (int*)(smem + 2*TPAD + 256);   // [256]
        float* scale_sh = smem + 2*TPAD + 512;

        // phase 1: sigmoid + pred + scale
        float sig[6];
        float s = 0.f;
        #pragma unroll
        for (int i = 0; i < 6; ++i) {
            int t = tid + i*256;
            sig[i] = 0.f;
            if (t < T_) {
                float x = audio[((size_t)b*T_ + t)*H_ + (H_-1)];
                sig[i] = 1.f / (1.f + expf(-x));
                s += sig[i];
            }
        }
        red[tid] = s; __syncthreads();
        for (int off = 128; off > 0; off >>= 1) {
            if (tid < off) red[tid] += red[tid+off];
            __syncthreads();
        }
        if (tid == 0) {
            float pred = red[0];
            pred_out[b] = pred;
            *scale_sh = (float)num_tokens[b] / pred;
        }
        __syncthreads();
        float scale = *scale_sh;
        #pragma unroll
        for (int i = 0; i < 6; ++i) {
            int t = tid + i*256;
            if (t < T_) al[t] = sig[i] * scale;
        }
        if (tid < TPAD - T_) al[T_ + tid] = 0.f;   // zero pad for batch-16 scan
        for (int m = tid; m < MTOK; m += 256) {
            lo[b*MTOK+m] = T_; hi[b*MTOK+m] = 0;
            h_sumsq[b*MTOK+m] = 0.f;         // zero for cif-epilogue atomics
        }
        if (tid == 0) lo[b*MTOK] = 0;
        __syncthreads();

        // phase 2: serial carry chain (lane 0), batch-16 double-buffered LDS
        // loads (hides ~120cy ds_read latency) + 2-op dep chain:
        // integ' = sx - floor(sx)  ==bitwise==  (sx>=1 ? sx-1 : sx) for sx in [0,2)
        if (tid == 0) {
            float integ = 0.f;
            float4 c0 = *(const float4*)&al[0];
            float4 c1 = *(const float4*)&al[4];
            float4 c2 = *(const float4*)&al[8];
            float4 c3 = *(const float4*)&al[12];
            for (int t = 0; t < TPAD; t += 16) {
                float4 n0, n1, n2, n3;
                if (t + 16 < TPAD) {
                    n0 = *(const float4*)&al[t+16];
                    n1 = *(const float4*)&al[t+20];
                    n2 = *(const float4*)&al[t+24];
                    n3 = *(const float4*)&al[t+28];
                }
                float4 o0, o1, o2, o3;
                float sx;
                o0.x = integ; sx = integ + c0.x; integ = sx - floorf(sx);
                o0.y = integ; sx = integ + c0.y; integ = sx - floorf(sx);
                o0.z = integ; sx = integ + c0.z; integ = sx - floorf(sx);
                o0.w = integ; sx = integ + c0.w; integ = sx - floorf(sx);
                o1.x = integ; sx = integ + c1.x; integ = sx - floorf(sx);
                o1.y = integ; sx = integ + c1.y; integ = sx - floorf(sx);
                o1.z = integ; sx = integ + c1.z; integ = sx - floorf(sx);
                o1.w = integ; sx = integ + c1.w; integ = sx - floorf(sx);
                o2.x = integ; sx = integ + c2.x; integ = sx - floorf(sx);
                o2.y = integ; sx = integ + c2.y; integ = sx - floorf(sx);
                o2.z = integ; sx = integ + c2.z; integ = sx - floorf(sx);
                o2.w = integ; sx = integ + c2.w; integ = sx - floorf(sx);
                o3.x = integ; sx = integ + c3.x; integ = sx - floorf(sx);
                o3.y = integ; sx = integ + c3.y; integ = sx - floorf(sx);
                o3.z = integ; sx = integ + c3.z; integ = sx - floorf(sx);
                o3.w = integ; sx = integ + c3.w; integ = sx - floorf(sx);
                *(float4*)&ip[t+0]  = o0;
                *(float4*)&ip[t+4]  = o1;
                *(float4*)&ip[t+8]  = o2;
                *(float4*)&ip[t+12] = o3;
                c0 = n0; c1 = n1; c2 = n2; c3 = n3;
            }
        }
        __syncthreads();

        // phase 3: parallel post-pass
        const int t0 = tid * 6;
        const int nm1 = num_tokens[b] - 1;
        int fires[6];
        int cnt = 0;
        if (t0 < T_) {
            #pragma unroll
            for (int j = 0; j < 6; ++j) {
                int t = t0 + j;
                float sx = ip[t] + al[t];     // same fp32 add as serial scan
                fires[j] = (sx >= 1.f) ? 1 : 0;
                cnt += fires[j];
            }
        }
        redI[tid] = cnt; __syncthreads();
        #pragma unroll
        for (int off = 1; off < 256; off <<= 1) {
            int v = redI[tid];
            if (tid >= off) v += redI[tid - off];
            __syncthreads();
            redI[tid] = v;
            __syncthreads();
        }
        if (t0 < T_) {
            int F = redI[tid] - cnt;
            const int base = b*T_;
            #pragma unroll
            for (int j = 0; j < 6; ++j) {
                int t = t0 + j;
                float a = al[t], ipv = ip[t];
                int fire = fires[j];
                F += fire;
                int tk1 = min(F, nm1);
                int tk0 = min(F - fire, nm1);
                float w0 = fire ? (1.f - ipv) : a;
                float w1 = (t < T_-1) ? (a - w0) : 0.f;
                tok0[base+t] = tk0;  w0a[base+t] = w0;
                tok1[base+t] = tk1;  w1a[base+t] = w1;
                if (tk1 != tk0) {
                    hi[b*MTOK + tk0] = t + 1;
                    lo[b*MTOK + tk1] = t;
                }
                if (t == T_-1) hi[b*MTOK + tk1] = T_;
            }
        }
    } else {
        // ================= transpose branch =================
        float (*tile)[33] = (float(*)[33])smem;
        int blk = blockIdx.x - B_;
        const float* src; u16* dst; int R, C, bx, by; bool scaled;
        if (blk < 1600) { src = cif_w;  dst = cwt; R = HM1; C = H_;   bx = blk % 40;  by = blk / 40;  scaled = false; }
        else { blk -= 1600; src = text_w; dst = twt; R = H_;  C = OUT_; bx = blk % 128; by = blk / 128; scaled = true; }
        int c0 = bx * 32, r0 = by * 32;
        int lx = tid & 31, ly = tid >> 5;  // 32 x 8
        #pragma unroll
        for (int j = 0; j < 4; ++j) {
            int r = r0 + ly + j*8;
            tile[ly + j*8][lx] = (r < R) ? src[(size_t)r*C + c0 + lx] : 0.f;
        }
        __syncthreads();
        // write value = src[r0+lx][c0+ly+j*8]; its k-index is r0+lx -> fold rms_w
        float rw = scaled ? rms_w[r0 + lx] : 1.f;
        #pragma unroll
        for (int j = 0; j < 4; ++j) {
            int c = c0 + ly + j*8;
            dst[(size_t)c*KPAD + r0 + lx] = f2bf(tile[lx][ly + j*8] * rw);
        }
    }
}

// K3: sparse pooling -> h1b bf16 [MROWS][KPAD], col 1279 = 0.
// Latency-optimized: weights staged to LDS, branchless float4 main loop.
__global__ __launch_bounds__(256) void k3_pool(
    const float* __restrict__ audio,
    const int* __restrict__ tok0, const float* __restrict__ w0a,
    const int* __restrict__ tok1, const float* __restrict__ w1a,
    const int* __restrict__ lo, const int* __restrict__ hi,
    u16* __restrict__ h1b)
{
    __shared__ float wl[1536];
    const int bm = blockIdx.x;
    const int b = bm / MTOK, m = bm % MTOK;
    const int l = lo[bm], h = hi[bm];
    const int tid = threadIdx.x;
    const int len = h - l;

    // stage combined weights (coalesced; removes scalar-load latency from loop)
    for (int j = tid; j < len; j += 256) {
        int i0 = b*T_ + l + j;
        float w = 0.f;
        if (tok0[i0] == m) w += w0a[i0];
        if (tok1[i0] == m) w += w1a[i0];
        wl[j] = w;
    }
    __syncthreads();

    const int d4 = tid * 4;          // covers 0..1023
    const int d1 = 1024 + tid;       // covers 1024..1279
    const float* rowp = audio + (size_t)(b*T_ + l) * H_;
    float4 acc4 = make_float4(0.f, 0.f, 0.f, 0.f);
    float acc1 = 0.f;
    #pragma unroll 4
    for (int j = 0; j < len; ++j) {
        float w = wl[j];
        const float* row = rowp + (size_t)j * H_;
        float4 r4 = *(const float4*)(row + d4);     // aligned: row stride 5120 B
        float r1 = (d1 < HM1) ? row[d1] : 0.f;
        acc4.x += w * r4.x; acc4.y += w * r4.y;
        acc4.z += w * r4.z; acc4.w += w * r4.w;
        acc1 += w * r1;
    }
    u16* dst = h1b + (size_t)bm * KPAD;
    ushort4 o;
    o.x = f2bf(acc4.x); o.y = f2bf(acc4.y); o.z = f2bf(acc4.z); o.w = f2bf(acc4.w);
    *(ushort4*)&dst[d4] = o;
    dst[d1] = (d1 < HM1) ? f2bf(acc1) : (u16)0;     // d1==1279 -> zero pad
}

// MFMA bf16 GEMM (B^T form), BK=32, 2-phase double-buffered K-loop
// (round-1 proven config: 48.6us text, VGPR 60, 3 blocks/CU):
// issue next K-step's global_load_lds into the alternate LDS buffer BEFORE
// ds_read+MFMA of the current step; single __syncthreads per step (its
// vmcnt(0) drain lands after a full step of compute -> latency overlapped
// by the 2-3 co-resident blocks' waves).
// CIF mode: bf16 out + per-row sum-of-squares atomics (pre-rounding fp32).
// TEXT mode: fp32 out, per-row 1/rms scale applied to acc (rms_w folded in Bt).
template<int TM, bool CIF>
__global__ __launch_bounds__(256, 3) void mfma_gemm_bt(
    const u16* __restrict__ A, const u16* __restrict__ Bt,
    const float* __restrict__ bias, void* __restrict__ Cv,
    float* __restrict__ h_sumsq, int M, int N)
{
    constexpr int K = KPAD;
    constexpr int NT = K / 32;          // 40 K-steps (even)
    constexpr int RA = TM / 64;
    constexpr int MI = 4;
    constexpr int NI = (TM == 128) ? 4 : 2;
    __shared__ u16 sA[2][TM*32];
    __shared__ u16 sB[2][128*32];
    const int tid = threadIdx.x;
    const int m0 = blockIdx.y * TM, n0 = blockIdx.x * 128;
    const int wave = tid >> 6, lane = tid & 63;
    const int wm = (TM == 128) ? (wave & 1) * 64 : 0;
    const int wn = (TM == 128) ? (wave >> 1) * 64 : wave * 32;
    const int lrow = lane & 15, quad = lane >> 4;

    const int r0 = tid >> 2, sl = tid & 3;
    const int q0 = sl ^ (r0 & 3) ^ ((r0 >> 2) & 3);
    const u16* Ag[RA];
    #pragma unroll
    for (int p = 0; p < RA; ++p)
        Ag[p] = A + (size_t)min(m0 + r0 + 64*p, M - 1) * K + q0 * 8;
    const u16* Bg[2];
    #pragma unroll
    for (int p = 0; p < 2; ++p)
        Bg[p] = Bt + (size_t)(n0 + r0 + 64*p) * K + q0 * 8;

    int offA[MI], offB[NI];
    #pragma unroll
    for (int i = 0; i < MI; ++i) {
        int m = wm + i*16 + lrow;
        offA[i] = m*32 + (quad ^ (m & 3) ^ ((m >> 2) & 3)) * 8;
    }
    #pragma unroll
    for (int i = 0; i < NI; ++i) {
        int n = wn + i*16 + lrow;
        offB[i] = n*32 + (quad ^ (n & 3) ^ ((n >> 2) & 3)) * 8;
    }

    f32x4 acc[MI][NI] = {};

    // prologue: stage K-step 0 into buffer 0, drain, barrier
    #pragma unroll
    for (int p = 0; p < RA; ++p) glds16(Ag[p], &sA[0][(tid + 256*p)*8]);
    #pragma unroll
    for (int p = 0; p < 2;  ++p) glds16(Bg[p], &sB[0][(tid + 256*p)*8]);
    __syncthreads();

    for (int t = 0; t < NT; t += 2) {
        // ---- even step: stage t+1 -> buf1, compute from buf0 ----
        {
            const int k1 = (t + 1) * 32;    // t+1 <= NT-1 always (NT even)
            #pragma unroll
            for (int p = 0; p < RA; ++p) glds16(Ag[p] + k1, &sA[1][(tid + 256*p)*8]);
            #pragma unroll
            for (int p = 0; p < 2;  ++p) glds16(Bg[p] + k1, &sB[1][(tid + 256*p)*8]);
            bf16x8 af[MI], bfr[NI];
            #pragma unroll
            for (int i = 0; i < MI; ++i) af[i]  = *(const bf16x8*)&sA[0][offA[i]];
            #pragma unroll
            for (int i = 0; i < NI; ++i) bfr[i] = *(const bf16x8*)&sB[0][offB[i]];
            #pragma unroll
            for (int mi = 0; mi < MI; ++mi)
                #pragma unroll
                for (int ni = 0; ni < NI; ++ni)
                    acc[mi][ni] = __builtin_amdgcn_mfma_f32_16x16x32_bf16(
                        af[mi], bfr[ni], acc[mi][ni], 0, 0, 0);
            __syncthreads();   // drains vmcnt(0): buf1 ready; all reads of buf0 done
        }
        // ---- odd step: stage t+2 -> buf0 (if any), compute from buf1 ----
        {
            const int k2 = (t + 2) * 32;
            if (t + 2 < NT) {
                #pragma unroll
                for (int p = 0; p < RA; ++p) glds16(Ag[p] + k2, &sA[0][(tid + 256*p)*8]);
                #pragma unroll
                for (int p = 0; p < 2;  ++p) glds16(Bg[p] + k2, &sB[0][(tid + 256*p)*8]);
            }
            bf16x8 af[MI], bfr[NI];
            #pragma unroll
            for (int i = 0; i < MI; ++i) af[i]  = *(const bf16x8*)&sA[1][offA[i]];
            #pragma unroll
            for (int i = 0; i < NI; ++i) bfr[i] = *(const bf16x8*)&sB[1][offB[i]];
            #pragma unroll
            for (int mi = 0; mi < MI; ++mi)
                #pragma unroll
                for (int ni = 0; ni < NI; ++ni)
                    acc[mi][ni] = __builtin_amdgcn_mfma_f32_16x16x32_bf16(
                        af[mi], bfr[ni], acc[mi][ni], 0, 0, 0);
            __syncthreads();
        }
    }

    // epilogue: C/D layout col=lane&15, row=quad*4+reg
    float bv[NI];
    #pragma unroll
    for (int ni = 0; ni < NI; ++ni) bv[ni] = bias[n0 + wn + ni*16 + lrow];

    #pragma unroll
    for (int mi = 0; mi < MI; ++mi) {
        #pragma unroll
        for (int r = 0; r < 4; ++r) {
            int row = m0 + wm + mi*16 + quad*4 + r;
            if (CIF) {
                float ss = 0.f;
                #pragma unroll
                for (int ni = 0; ni < NI; ++ni) {
                    float v = acc[mi][ni][r] + bv[ni];
                    ss += v * v;
                    if (row < M)
                        ((u16*)Cv)[(size_t)row*N + (n0 + wn + ni*16 + lrow)] = f2bf(v);
                }
                // reduce ss over the 16 lanes (lrow) sharing this row
                ss += __shfl_xor(ss, 1);
                ss += __shfl_xor(ss, 2);
                ss += __shfl_xor(ss, 4);
                ss += __shfl_xor(ss, 8);
                if (lrow == 0 && row < M) atomicAdd(&h_sumsq[row], ss);
            } else {
                float inv = 1.f;
                if (row < M)
                    inv = 1.f / sqrtf(h_sumsq[row] / (float)H_ + 1e-6f);
                #pragma unroll
                for (int ni = 0; ni < NI; ++ni) {
                    if (row < M)
                        ((float*)Cv)[(size_t)row*N + (n0 + wn + ni*16 + lrow)] =
                            acc[mi][ni][r] * inv + bv[ni];
                }
            }
        }
    }
}

extern "C" void kernel_launch(void* const* d_in, const int* in_sizes, int n_in,
                              void* d_out, int out_size, void* d_ws, size_t ws_size,
                              hipStream_t stream) {
    (void)in_sizes; (void)n_in; (void)out_size; (void)ws_size;
    const float* audio      = (const float*)d_in[0];
    const int*   num_tokens = (const int*)d_in[1];
    const float* rms_w      = (const float*)d_in[2];
    const float* cif_w      = (const float*)d_in[3];
    const float* cif_b      = (const float*)d_in[4];
    const float* text_w     = (const float*)d_in[5];
    const float* text_b     = (const float*)d_in[6];

    float* out  = (float*)d_out;                   // fp32 output
    float* pred = out + (size_t)MROWS * OUT_;      // pred_num_tokens tail (8 floats)

    char* ws = (char*)d_ws;
    float* h_sumsq = (float*)(ws + 0);         // 12000 B (zeroed in k_front)
    float* w0a  = (float*)(ws + 48000);
    float* w1a  = (float*)(ws + 96000);
    int*   tok0 = (int*)  (ws + 144000);
    int*   tok1 = (int*)  (ws + 192000);
    int*   lo   = (int*)  (ws + 240000);
    int*   hi   = (int*)  (ws + 252000);
    // DISJOINT regions (no lifetime aliasing):
    u16* h1b = (u16*)(ws + 264192);     //  7,680,000 B
    u16* cwt = (u16*)(ws + 7944192);    //  3,276,800 B
    u16* twt = (u16*)(ws + 11220992);   // 10,485,760 B  (rms_w folded in)
    u16* hX  = (u16*)(ws + 21706752);   //  7,680,000 B  (cif out, unnormalized)
    // total ws usage: 29,386,752 B

    // scan (blocks 0..7) + weight transposes (blocks 8..6727)
    k_front<<<B_ + 1600 + 5120, 256, 0, stream>>>(
        audio, num_tokens, rms_w, pred, tok0, w0a, tok1, w1a, lo, hi,
        h_sumsq, cif_w, text_w, cwt, twt);
    k3_pool<<<MROWS, 256, 0, stream>>>(audio, tok0, w0a, tok1, w1a, lo, hi, h1b);
    // cif_proj (bf16 out + row sumsq): hX = h1b . cwt^T + cif_b
    mfma_gemm_bt<64, true><<<dim3(H_/128, (MROWS+63)/64), 256, 0, stream>>>(
        h1b, cwt, cif_b, hX, h_sumsq, MROWS, H_);
    // text_proj (fp32 out, 1/rms applied in epilogue): out = norm(hX) . twt^T + text_b
    mfma_gemm_bt<128, false><<<dim3(OUT_/128, (MROWS+127)/128), 256, 0, stream>>>(
        hX, twt, text_b, out, h_sumsq, MROWS, OUT_);
}